// Round 3
// baseline (655.586 us; speedup 1.0000x reference)
//
#include <hip/hip_runtime.h>
#include <hip/hip_bf16.h>
#include <math.h>

#define B_ROWS 32768
#define NBLK 12

typedef __attribute__((ext_vector_type(8)))  short        s8v;   // 8 x bf16
typedef __attribute__((ext_vector_type(4)))  float        f4v;
typedef __attribute__((ext_vector_type(2)))  unsigned int u2v;

__device__ __forceinline__ short f2bf(float f){            // f32 -> bf16 RNE
  unsigned u = __builtin_bit_cast(unsigned, f);
  u = (u + 0x7fffu + ((u >> 16) & 1u)) >> 16;
  return (short)u;
}

#define MFMA16(A,B,C) __builtin_amdgcn_mfma_f32_16x16x32_bf16((A),(B),(C),0,0,0)

// ---------------- LDS layout (bytes) ----------------
#define OXFT 0        // f32 [64][132] x-state transposed [dim][batch]
#define XFT_S 132
#define OXHB 33792    // bf16 [128][40] x-half MLP input [batch][k]
#define XHB_S 40
#define OHB  44032    // bf16 [128][264] hidden chunk [batch][hid_local 256], pad 8
#define HB_S 264
#define ORB  111616   // f32 [128][68] r [batch][out 64], pad 4
#define RB_S 68
#define OLJ  146432   // f32[128]
#define OPERM 146944  // int[64]
#define OELS 147200   // f32[64]
#define OBIV 147456   // f32[64]
#define OSLS 147712   // f32 scalar
#define SM_SZ 147728

// ws (bf16 weights) element offsets
#define O_S1W1 0
#define O_S1W2 983040
#define O_S2W1 1376256
#define O_S2W2 2359296
#define W_TOTAL 2752512

// -------- one-time f32 -> bf16 weight conversion --------
__global__ void cvtw(const float* __restrict__ s1w1, const float* __restrict__ s1w2,
                     const float* __restrict__ s2w1, const float* __restrict__ s2w2,
                     unsigned short* __restrict__ dst)
{
  long t = (long)blockIdx.x * blockDim.x + threadIdx.x;
  if (t >= W_TOTAL) return;
  float v;
  if      (t < O_S1W2) v = s1w1[t];
  else if (t < O_S2W1) v = s1w2[t - O_S1W2];
  else if (t < O_S2W2) v = s2w1[t - O_S2W1];
  else                 v = s2w2[t - O_S2W2];
  dst[t] = (unsigned short)f2bf(v);
}

// -------- weight A-fragment load (global, bf16 or f32 fallback) --------
template<int USEBF>
__device__ __forceinline__ s8v ldw(const unsigned short* wb, const float* wf, int off){
  if (USEBF){
    return *(const s8v*)(wb + off);
  } else {
    f4v a = *(const f4v*)(wf + off);
    f4v b = *(const f4v*)(wf + off + 4);
    s8v r;
    r[0]=f2bf(a[0]); r[1]=f2bf(a[1]); r[2]=f2bf(a[2]); r[3]=f2bf(a[3]);
    r[4]=f2bf(b[0]); r[5]=f2bf(b[1]); r[6]=f2bf(b[2]); r[7]=f2bf(b[3]);
    return r;
  }
}

// ---- one MLP (transposed, 16x16x32 everywhere, chunked h through LDS) ----
// PHASE 0: s2 weights, updates x dims 0..31 (y1), writes XHB=y1
// PHASE 1: s1 weights, updates x dims 32..63 (y2)
template<int PHASE, int USEBF>
__device__ __forceinline__ void mlp16(char* sm, int tid,
    const unsigned short* w1b, const float* w1f,
    const unsigned short* w2b, const float* w2f,
    const float* b1g, const float* b2g, const s8v hfr[4][4])
{
  const int lane = tid & 63, wave = tid >> 6;
  const int hw = wave >> 1, ng = wave & 1;   // hw: hidden-tile group (G1) / out-tile (G2); ng: batch half
  const int l15 = lane & 15, lq = lane >> 4;
  short* XHB = (short*)(sm + OXHB);
  short* HB  = (short*)(sm + OHB);
  float* XFT = (float*)(sm + OXFT);
  float* RB  = (float*)(sm + ORB);
  float* LOGJ= (float*)(sm + OLJ);

  // x-part B-frags (k=0..31), register-resident for both chunks
  s8v xk[4];
  #pragma unroll
  for (int nt = 0; nt < 4; ++nt)
    xk[nt] = *(const s8v*)(XHB + (ng*64 + nt*16 + l15)*XHB_S + lq*8);

  // GEMM2 accumulators (one 16x16 out-tile per wave, 4 batch-tiles), bias-init
  f4v racc[4];
  { f4v bv = *(const f4v*)(b2g + hw*16 + lq*4);
    #pragma unroll
    for (int nt = 0; nt < 4; ++nt) racc[nt] = bv; }

  #pragma unroll
  for (int c = 0; c < 2; ++c){
    // ---- GEMM1 chunk: h^T rows c*256+hw*64..+63, batches ng*64..+63
    f4v acc[4][4];
    #pragma unroll
    for (int mt = 0; mt < 4; ++mt){
      f4v bv = *(const f4v*)(b1g + c*256 + hw*64 + mt*16 + lq*4);
      #pragma unroll
      for (int nt = 0; nt < 4; ++nt) acc[mt][nt] = bv;
    }
    #pragma unroll
    for (int kk = 0; kk < 5; ++kk){
      s8v a[4];
      #pragma unroll
      for (int mt = 0; mt < 4; ++mt)
        a[mt] = ldw<USEBF>(w1b, w1f, (c*256 + hw*64 + mt*16 + l15)*160 + kk*32 + lq*8);
      #pragma unroll
      for (int nt = 0; nt < 4; ++nt){
        s8v bb = (kk == 0) ? xk[nt] : hfr[nt][kk-1];
        #pragma unroll
        for (int mt = 0; mt < 4; ++mt)
          acc[mt][nt] = MFMA16(a[mt], bb, acc[mt][nt]);
      }
    }
    // relu + pack + write h chunk to LDS [batch][hid_local]
    #pragma unroll
    for (int mt = 0; mt < 4; ++mt)
      #pragma unroll
      for (int nt = 0; nt < 4; ++nt){
        float h0 = fmaxf(acc[mt][nt][0], 0.f), h1 = fmaxf(acc[mt][nt][1], 0.f);
        float h2 = fmaxf(acc[mt][nt][2], 0.f), h3 = fmaxf(acc[mt][nt][3], 0.f);
        unsigned u0 = (unsigned)(unsigned short)f2bf(h0) | ((unsigned)(unsigned short)f2bf(h1) << 16);
        unsigned u1 = (unsigned)(unsigned short)f2bf(h2) | ((unsigned)(unsigned short)f2bf(h3) << 16);
        *(u2v*)(HB + (ng*64 + nt*16 + l15)*HB_S + hw*64 + mt*16 + lq*4) = (u2v){u0, u1};
      }
    __syncthreads();
    // ---- GEMM2 partial over this chunk (K=256): out rows hw*16, batches ng*64..+63
    #pragma unroll
    for (int kk = 0; kk < 8; ++kk){
      s8v aw = ldw<USEBF>(w2b, w2f, (hw*16 + l15)*512 + c*256 + kk*32 + lq*8);
      #pragma unroll
      for (int nt = 0; nt < 4; ++nt){
        s8v bb = *(const s8v*)(HB + (ng*64 + nt*16 + l15)*HB_S + kk*32 + lq*8);
        racc[nt] = MFMA16(aw, bb, racc[nt]);
      }
    }
    __syncthreads();
  }

  // write r (f32) to RB [batch][out]
  #pragma unroll
  for (int nt = 0; nt < 4; ++nt)
    *(f4v*)(RB + (ng*64 + nt*16 + l15)*RB_S + hw*16 + lq*4) = racc[nt];
  __syncthreads();

  // ---- coupling: le = 0.636*atan(r[:32]); y = exp(le)*x_half + r[32:]
  {
    int b = tid & 127, og = tid >> 7;
    f4v L0 = *(const f4v*)(RB + b*RB_S + og*8);
    f4v L1 = *(const f4v*)(RB + b*RB_S + og*8 + 4);
    f4v R0 = *(const f4v*)(RB + b*RB_S + 32 + og*8);
    f4v R1 = *(const f4v*)(RB + b*RB_S + 32 + og*8 + 4);
    float le[8] = {L0[0],L0[1],L0[2],L0[3],L1[0],L1[1],L1[2],L1[3]};
    float ra[8] = {R0[0],R0[1],R0[2],R0[3],R1[0],R1[1],R1[2],R1[3]};
    float part = 0.f;
    s8v yv;
    #pragma unroll
    for (int j = 0; j < 8; ++j){
      float l = 0.636f * atanf(le[j]);
      int d = PHASE*32 + og*8 + j;
      float y = __expf(l) * XFT[d*XFT_S + b] + ra[j];
      XFT[d*XFT_S + b] = y;
      yv[j] = f2bf(y);
      part += l;
    }
    if (PHASE == 0) *(s8v*)(XHB + b*XHB_S + og*8) = yv;  // y1 feeds MLP1 x-part
    atomicAdd(&LOGJ[b], part);
  }
  __syncthreads();
}

template<int USEBF>
__global__ __launch_bounds__(512, 1) void cinn_t(
    const float* __restrict__ q, const float* __restrict__ Hg,
    const int* __restrict__ perms,
    const float* __restrict__ ls_g, const float* __restrict__ bi_g,
    const float* __restrict__ s1b1, const float* __restrict__ s1b2,
    const float* __restrict__ s2b1, const float* __restrict__ s2b2,
    const unsigned short* __restrict__ wbf,
    const float* __restrict__ s1W1f, const float* __restrict__ s1W2f,
    const float* __restrict__ s2W1f, const float* __restrict__ s2W2f,
    float* __restrict__ outz, float* __restrict__ outlj)
{
  __shared__ __align__(16) char sm[SM_SZ];
  const int tid = threadIdx.x;
  const int rowbase = blockIdx.x * 128;
  const int lane = tid & 63, wave = tid >> 6;
  const int ng = wave & 1;
  const int l15 = lane & 15, lq = lane >> 4;

  float* XFT = (float*)(sm + OXFT);
  float* LOGJ = (float*)(sm + OLJ);
  int*   PERM = (int*)(sm + OPERM);
  float* ELS  = (float*)(sm + OELS);
  float* BIV  = (float*)(sm + OBIV);
  float* SLSp = (float*)(sm + OSLS);
  short* XHB  = (short*)(sm + OXHB);

  // init XFT from q: coalesced read, strided LDS write (once)
  {
    int b = tid >> 2, j = tid & 3;
    const float* src = q + (size_t)(rowbase + b)*64 + j*16;
    #pragma unroll
    for (int i = 0; i < 4; ++i){
      f4v v = *(const f4v*)(src + 4*i);
      #pragma unroll
      for (int jj = 0; jj < 4; ++jj)
        XFT[(j*16 + 4*i + jj)*XFT_S + b] = v[jj];
    }
  }
  if (tid < 128) LOGJ[tid] = 0.f;
  if (tid == 0)  *SLSp = 0.f;
  __syncthreads();
  if (tid < 64){
    float p = 0.f;
    #pragma unroll
    for (int k = 0; k < NBLK; ++k) p += ls_g[k*64 + tid];
    atomicAdd(SLSp, p);
  }

  // H-part B-fragments (k=32..159): loaded ONCE, register-resident
  s8v hfr[4][4];
  #pragma unroll
  for (int nt = 0; nt < 4; ++nt){
    int b = rowbase + ng*64 + nt*16 + l15;
    #pragma unroll
    for (int kkh = 0; kkh < 4; ++kkh){
      const float* hp = Hg + (size_t)b*128 + kkh*32 + lq*8;
      f4v a = *(const f4v*)hp;
      f4v c = *(const f4v*)(hp + 4);
      s8v r;
      r[0]=f2bf(a[0]); r[1]=f2bf(a[1]); r[2]=f2bf(a[2]); r[3]=f2bf(a[3]);
      r[4]=f2bf(c[0]); r[5]=f2bf(c[1]); r[6]=f2bf(c[2]); r[7]=f2bf(c[3]);
      hfr[nt][kkh] = r;
    }
  }

  for (int blk = 0; blk < NBLK; ++blk){
    if (tid < 64){
      PERM[tid] = perms[blk*64 + tid];
      ELS[tid]  = __expf(ls_g[blk*64 + tid]);
      BIV[tid]  = bi_g[blk*64 + tid];
    }
    __syncthreads();

    // permute + affine on XFT (read-all / barrier / write-all)
    {
      int d = lane, bg = wave;
      int pd = PERM[d];
      f4v v[4];
      #pragma unroll
      for (int i = 0; i < 4; ++i)
        v[i] = *(const f4v*)(XFT + pd*XFT_S + bg*16 + 4*i);
      __syncthreads();
      float e = ELS[d], bi = BIV[d];
      #pragma unroll
      for (int i = 0; i < 4; ++i){
        #pragma unroll
        for (int jj = 0; jj < 4; ++jj) v[i][jj] = fmaf(v[i][jj], e, bi);
        *(f4v*)(XFT + d*XFT_S + bg*16 + 4*i) = v[i];
      }
      if (d >= 32){  // x2 -> XHB (MLP2 input)
        #pragma unroll
        for (int i = 0; i < 4; ++i)
          #pragma unroll
          for (int jj = 0; jj < 4; ++jj)
            XHB[(bg*16 + 4*i + jj)*XHB_S + (d - 32)] = f2bf(v[i][jj]);
      }
    }
    __syncthreads();

    // MLP2 (s2 weights) -> y1 (dims 0..31)
    mlp16<0, USEBF>(sm, tid,
        wbf + O_S2W1 + (size_t)blk*81920, s2W1f + (size_t)blk*81920,
        wbf + O_S2W2 + (size_t)blk*32768, s2W2f + (size_t)blk*32768,
        s2b1 + blk*512, s2b2 + blk*64, hfr);

    // MLP1 (s1 weights) -> y2 (dims 32..63)
    mlp16<1, USEBF>(sm, tid,
        wbf + O_S1W1 + (size_t)blk*81920, s1W1f + (size_t)blk*81920,
        wbf + O_S1W2 + (size_t)blk*32768, s1W2f + (size_t)blk*32768,
        s1b1 + blk*512, s1b2 + blk*64, hfr);
  }

  // output: transpose back, coalesced global writes
  {
    int b = tid >> 2, j = tid & 3;
    float* dst = outz + (size_t)(rowbase + b)*64 + j*16;
    #pragma unroll
    for (int i = 0; i < 4; ++i){
      f4v w;
      #pragma unroll
      for (int jj = 0; jj < 4; ++jj)
        w[jj] = XFT[(j*16 + 4*i + jj)*XFT_S + b];
      *(f4v*)(dst + 4*i) = w;
    }
  }
  if (tid < 128) outlj[rowbase + tid] = LOGJ[tid] + *SLSp;
}

extern "C" void kernel_launch(void* const* d_in, const int* in_sizes, int n_in,
                              void* d_out, int out_size, void* d_ws, size_t ws_size,
                              hipStream_t stream)
{
  const float* q    = (const float*)d_in[0];
  const float* Hg   = (const float*)d_in[1];
  const int*   perms= (const int*)  d_in[2];
  const float* ls   = (const float*)d_in[3];
  const float* bi   = (const float*)d_in[4];
  const float* s1W1 = (const float*)d_in[5];
  const float* s1b1 = (const float*)d_in[6];
  const float* s1W2 = (const float*)d_in[7];
  const float* s1b2 = (const float*)d_in[8];
  const float* s2W1 = (const float*)d_in[9];
  const float* s2b1 = (const float*)d_in[10];
  const float* s2W2 = (const float*)d_in[11];
  const float* s2b2 = (const float*)d_in[12];
  float* outz  = (float*)d_out;
  float* outlj = outz + (size_t)B_ROWS * 64;

  int usebf = (ws_size >= (size_t)W_TOTAL * 2) ? 1 : 0;
  unsigned short* wbf = (unsigned short*)d_ws;
  if (usebf){
    cvtw<<<2688, 1024, 0, stream>>>(s1W1, s1W2, s2W1, s2W2, wbf);
    cinn_t<1><<<256, 512, 0, stream>>>(q, Hg, perms, ls, bi,
                                       s1b1, s1b2, s2b1, s2b2,
                                       wbf, s1W1, s1W2, s2W1, s2W2,
                                       outz, outlj);
  } else {
    cinn_t<0><<<256, 512, 0, stream>>>(q, Hg, perms, ls, bi,
                                       s1b1, s1b2, s2b1, s2b2,
                                       wbf, s1W1, s1W2, s2W1, s2W2,
                                       outz, outlj);
  }
}

// Round 4
// 299.668 us; speedup vs baseline: 2.1877x; 2.1877x over previous
//
#include <hip/hip_runtime.h>
#include <hip/hip_bf16.h>
#include <math.h>

#define B_ROWS 32768

typedef __attribute__((ext_vector_type(8)))  short        s8v;
typedef __attribute__((ext_vector_type(4)))  float        f4v;
typedef __attribute__((ext_vector_type(2)))  unsigned int u2v;
typedef __attribute__((ext_vector_type(4)))  unsigned int u4v;

__device__ __forceinline__ short f2bf(float f){            // f32 -> bf16 RNE
  unsigned u = __builtin_bit_cast(unsigned, f);
  u = (u + 0x7fffu + ((u >> 16) & 1u)) >> 16;
  return (short)u;
}

#define MFMA16(A,B,C) __builtin_amdgcn_mfma_f32_16x16x32_bf16((A),(B),(C),0,0,0)

// ---------------- LDS layout (bytes) ----------------
#define OXFT 0        // f32 [64][132] x-state transposed [dim][batch]
#define XFT_S 132
#define OHB  33792    // bf16 [128][136] hidden chunk  /  f32 [128][68] r (aliased)
#define HB_S 136
#define RB_S 68
#define OW1  68608    // 2 x bf16 [128][168] W1 chunk double buffer
#define W1BUF 43008
#define W1_S 168
#define OB1  154624   // 2 x f32[512] b1 double buffer
#define OB2  158720   // 2 x f32[64]  b2 double buffer
#define OLJ  159232   // f32[128]
#define OPERM 159744  // int[64]
#define OELS 160000   // f32[64]
#define OBIV 160256   // f32[64]
#define OSLS 160512   // f32 scalar
#define SM_SZ 160528

// ws (bf16 weights) element offsets
#define O_S1W1 0
#define O_S1W2 983040
#define O_S2W1 1376256
#define O_S2W2 2359296
#define W_TOTAL 2752512

// -------- one-time f32 -> bf16 weight conversion --------
__global__ void cvtw(const float* __restrict__ s1w1, const float* __restrict__ s1w2,
                     const float* __restrict__ s2w1, const float* __restrict__ s2w2,
                     unsigned short* __restrict__ dst)
{
  long t = (long)blockIdx.x * blockDim.x + threadIdx.x;
  if (t >= W_TOTAL) return;
  float v;
  if      (t < O_S1W2) v = s1w1[t];
  else if (t < O_S2W1) v = s1w2[t - O_S1W2];
  else if (t < O_S2W2) v = s2w1[t - O_S2W1];
  else                 v = s2w2[t - O_S2W2];
  dst[t] = (unsigned short)f2bf(v);
}

template<int USEBF>
__device__ __forceinline__ s8v ldw(const unsigned short* wb, const float* wf, int off){
  if (USEBF){
    return *(const s8v*)(wb + off);
  } else {
    f4v a = *(const f4v*)(wf + off);
    f4v b = *(const f4v*)(wf + off + 4);
    s8v r;
    r[0]=f2bf(a[0]); r[1]=f2bf(a[1]); r[2]=f2bf(a[2]); r[3]=f2bf(a[3]);
    r[4]=f2bf(b[0]); r[5]=f2bf(b[1]); r[6]=f2bf(b[2]); r[7]=f2bf(b[3]);
    return r;
  }
}

struct MP { const unsigned short* w1b; const float* w1f;
            const unsigned short* w2b; const float* w2f;
            const float* b1; const float* b2; };

__device__ __forceinline__ MP getmp(int m, const unsigned short* wbf,
    const float* s1W1f, const float* s1W2f, const float* s2W1f, const float* s2W2f,
    const float* s1b1, const float* s1b2, const float* s2b1, const float* s2b2)
{
  int blk = m >> 1;
  MP r;
  if (m & 1){
    r.w1b = wbf + O_S1W1 + (size_t)blk*81920; r.w1f = s1W1f + (size_t)blk*81920;
    r.w2b = wbf + O_S1W2 + (size_t)blk*32768; r.w2f = s1W2f + (size_t)blk*32768;
    r.b1 = s1b1 + blk*512; r.b2 = s1b2 + blk*64;
  } else {
    r.w1b = wbf + O_S2W1 + (size_t)blk*81920; r.w1f = s2W1f + (size_t)blk*81920;
    r.w2b = wbf + O_S2W2 + (size_t)blk*32768; r.w2f = s2W2f + (size_t)blk*32768;
    r.b1 = s2b1 + blk*512; r.b2 = s2b2 + blk*64;
  }
  return r;
}

// issue coalesced global loads of one 128-hidden W1 chunk into registers
template<int USEBF>
__device__ __forceinline__ void issue_w1(const MP& p, int cchunk, int tid,
                                         u4v wt[5], f4v wtf[10])
{
  if (USEBF){
    const unsigned short* s = p.w1b + cchunk*20480;
    #pragma unroll
    for (int k = 0; k < 5; ++k) wt[k] = *(const u4v*)(s + (size_t)(k*512+tid)*8);
  } else {
    const float* s = p.w1f + cchunk*20480;
    #pragma unroll
    for (int k = 0; k < 10; ++k) wtf[k] = *(const f4v*)(s + (size_t)(k*512+tid)*4);
  }
}

// write staged W1 registers into padded LDS buffer
template<int USEBF>
__device__ __forceinline__ void write_w1(char* sm, int buf, int tid,
                                         const u4v wt[5], const f4v wtf[10])
{
  short* W1n = (short*)(sm + OW1 + buf*W1BUF);
  if (USEBF){
    #pragma unroll
    for (int k = 0; k < 5; ++k){
      int i = k*512 + tid, row = i/20, c16 = i - row*20;
      *(u4v*)(W1n + row*W1_S + c16*8) = wt[k];
    }
  } else {
    #pragma unroll
    for (int k = 0; k < 10; ++k){
      int i = k*512 + tid, row = i/40, c4 = i - row*40;
      f4v v = wtf[k];
      unsigned u0 = (unsigned)(unsigned short)f2bf(v[0]) | ((unsigned)(unsigned short)f2bf(v[1])<<16);
      unsigned u1 = (unsigned)(unsigned short)f2bf(v[2]) | ((unsigned)(unsigned short)f2bf(v[3])<<16);
      *(u2v*)(W1n + row*W1_S + c4*4) = (u2v){u0,u1};
    }
  }
}

template<int USEBF>
__device__ __forceinline__ void load_w2(const MP& p, int c, int hw, int l15, int lq, s8v w2o[4]){
  #pragma unroll
  for (int kk = 0; kk < 4; ++kk)
    w2o[kk] = ldw<USEBF>(p.w2b, p.w2f, (hw*16 + l15)*512 + c*128 + kk*32 + lq*8);
}

// ---- one MLP: h^T = relu(W1 x^T + b1); r^T = W2 h^T + b2; coupling ----
template<int USEBF>
__device__ __forceinline__ void mlp_body(char* sm, int tid, int m,
    const MP& cur, const MP& nxt, const s8v hfr[4][4], s8v w2cur[4])
{
  const int lane = tid & 63, wave = tid >> 6;
  const int hw = wave >> 1, ng = wave & 1;
  const int l15 = lane & 15, lq = lane >> 4;
  const int bp = m & 1;
  float* XFT = (float*)(sm + OXFT);
  short* HB  = (short*)(sm + OHB);
  float* RB  = (float*)(sm + OHB);
  float* B1L = (float*)(sm + OB1);
  float* B2L = (float*)(sm + OB2);
  float* LOGJ= (float*)(sm + OLJ);

  // x-part B-frags straight from XFT (dims xbase..xbase+31)
  const int xbase = bp ? 0 : 32;
  s8v xk[4];
  #pragma unroll
  for (int nt = 0; nt < 4; ++nt){
    int b = ng*64 + nt*16 + l15;
    s8v v;
    #pragma unroll
    for (int i = 0; i < 8; ++i)
      v[i] = f2bf(XFT[(xbase + lq*8 + i)*XFT_S + b]);
    xk[nt] = v;
  }

  // GEMM2 accumulators, bias-init (wave owns out-tile hw, batches ng*64..+63)
  f4v racc[4];
  { f4v bv = *(const f4v*)(B2L + bp*64 + hw*16 + lq*4);
    #pragma unroll
    for (int nt = 0; nt < 4; ++nt) racc[nt] = bv; }

  #pragma unroll
  for (int c = 0; c < 4; ++c){
    // ---- prefetch: next W1 chunk, next W2 frags, (c==3) next MLP biases
    u4v wt[5]; f4v wtf[10];
    s8v w2n[4];
    const MP& pn = (c < 3) ? cur : nxt;
    const int cn = (c < 3) ? c + 1 : 0;
    issue_w1<USEBF>(pn, cn, tid, wt, wtf);
    load_w2<USEBF>(pn, cn, hw, l15, lq, w2n);
    float b1t = 0.f, b2t = 0.f;
    if (c == 3){
      b1t = nxt.b1[tid];
      if (tid < 64) b2t = nxt.b2[tid];
    }

    // ---- GEMM1 chunk c: hidden rows c*128 + hw*32 + {0,16}, from LDS weights
    const short* W1c = (const short*)(sm + OW1 + (c&1)*W1BUF);
    f4v acc[2][4];
    #pragma unroll
    for (int mt = 0; mt < 2; ++mt){
      f4v bv = *(const f4v*)(B1L + bp*512 + c*128 + hw*32 + mt*16 + lq*4);
      #pragma unroll
      for (int nt = 0; nt < 4; ++nt) acc[mt][nt] = bv;
    }
    #pragma unroll
    for (int kk = 0; kk < 5; ++kk){
      s8v a0 = *(const s8v*)(W1c + (hw*32 +  0 + l15)*W1_S + kk*32 + lq*8);
      s8v a1 = *(const s8v*)(W1c + (hw*32 + 16 + l15)*W1_S + kk*32 + lq*8);
      #pragma unroll
      for (int nt = 0; nt < 4; ++nt){
        s8v bb = (kk == 0) ? xk[nt] : hfr[nt][kk-1];
        acc[0][nt] = MFMA16(a0, bb, acc[0][nt]);
        acc[1][nt] = MFMA16(a1, bb, acc[1][nt]);
      }
    }
    // relu + pack -> HB [batch][hid_local]
    #pragma unroll
    for (int mt = 0; mt < 2; ++mt)
      #pragma unroll
      for (int nt = 0; nt < 4; ++nt){
        float h0 = fmaxf(acc[mt][nt][0],0.f), h1 = fmaxf(acc[mt][nt][1],0.f);
        float h2 = fmaxf(acc[mt][nt][2],0.f), h3 = fmaxf(acc[mt][nt][3],0.f);
        unsigned u0 = (unsigned)(unsigned short)f2bf(h0) | ((unsigned)(unsigned short)f2bf(h1)<<16);
        unsigned u1 = (unsigned)(unsigned short)f2bf(h2) | ((unsigned)(unsigned short)f2bf(h3)<<16);
        *(u2v*)(HB + (ng*64 + nt*16 + l15)*HB_S + hw*32 + mt*16 + lq*4) = (u2v){u0,u1};
      }
    // commit staged weights (loads have had the whole GEMM1 to land)
    write_w1<USEBF>(sm, cn & 1, tid, wt, wtf);
    if (c == 3){
      B1L[(bp^1)*512 + tid] = b1t;
      if (tid < 64) B2L[(bp^1)*64 + tid] = b2t;
    }
    __syncthreads();

    // ---- GEMM2 partial over this chunk (K=128), W2 frags from registers
    #pragma unroll
    for (int kk = 0; kk < 4; ++kk){
      s8v aw = w2cur[kk];
      #pragma unroll
      for (int nt = 0; nt < 4; ++nt){
        s8v bb = *(const s8v*)(HB + (ng*64 + nt*16 + l15)*HB_S + kk*32 + lq*8);
        racc[nt] = MFMA16(aw, bb, racc[nt]);
      }
    }
    #pragma unroll
    for (int kk = 0; kk < 4; ++kk) w2cur[kk] = w2n[kk];
    __syncthreads();
  }

  // write r (f32) to RB [batch][out] (aliases HB; reads all done)
  #pragma unroll
  for (int nt = 0; nt < 4; ++nt)
    *(f4v*)(RB + (ng*64 + nt*16 + l15)*RB_S + hw*16 + lq*4) = racc[nt];
  __syncthreads();

  // ---- coupling: le = 0.636*atan(r[:32]); y = exp(le)*x_half + r[32:]
  {
    int b = tid & 127, og = tid >> 7;
    f4v L0 = *(const f4v*)(RB + b*RB_S + og*8);
    f4v L1 = *(const f4v*)(RB + b*RB_S + og*8 + 4);
    f4v R0 = *(const f4v*)(RB + b*RB_S + 32 + og*8);
    f4v R1 = *(const f4v*)(RB + b*RB_S + 32 + og*8 + 4);
    float le[8] = {L0[0],L0[1],L0[2],L0[3],L1[0],L1[1],L1[2],L1[3]};
    float ra[8] = {R0[0],R0[1],R0[2],R0[3],R1[0],R1[1],R1[2],R1[3]};
    float part = 0.f;
    #pragma unroll
    for (int j = 0; j < 8; ++j){
      float l = 0.636f * atanf(le[j]);
      int d = bp*32 + og*8 + j;
      float y = __expf(l) * XFT[d*XFT_S + b] + ra[j];
      XFT[d*XFT_S + b] = y;
      part += l;
    }
    atomicAdd(&LOGJ[b], part);
  }
  __syncthreads();
}

template<int USEBF>
__global__ __launch_bounds__(512, 2) void cinn_t(
    const float* __restrict__ q, const float* __restrict__ Hg,
    const int* __restrict__ perms,
    const float* __restrict__ ls_g, const float* __restrict__ bi_g,
    const float* __restrict__ s1b1, const float* __restrict__ s1b2,
    const float* __restrict__ s2b1, const float* __restrict__ s2b2,
    const unsigned short* __restrict__ wbf,
    const float* __restrict__ s1W1f, const float* __restrict__ s1W2f,
    const float* __restrict__ s2W1f, const float* __restrict__ s2W2f,
    float* __restrict__ outz, float* __restrict__ outlj)
{
  __shared__ __align__(16) char sm[SM_SZ];
  const int tid = threadIdx.x;
  const int rowbase = blockIdx.x * 128;
  const int lane = tid & 63, wave = tid >> 6;
  const int hw = wave >> 1, ng = wave & 1;
  const int l15 = lane & 15, lq = lane >> 4;

  float* XFT = (float*)(sm + OXFT);
  float* B1L = (float*)(sm + OB1);
  float* B2L = (float*)(sm + OB2);
  float* LOGJ = (float*)(sm + OLJ);
  int*   PERM = (int*)(sm + OPERM);
  float* ELS  = (float*)(sm + OELS);
  float* BIV  = (float*)(sm + OBIV);
  float* SLSp = (float*)(sm + OSLS);

  // init XFT from q (coalesced read, strided LDS write, once)
  {
    int b = tid >> 2, j = tid & 3;
    const float* src = q + (size_t)(rowbase + b)*64 + j*16;
    #pragma unroll
    for (int i = 0; i < 4; ++i){
      f4v v = *(const f4v*)(src + 4*i);
      #pragma unroll
      for (int jj = 0; jj < 4; ++jj)
        XFT[(j*16 + 4*i + jj)*XFT_S + b] = v[jj];
    }
  }
  if (tid < 128) LOGJ[tid] = 0.f;
  if (tid == 0)  *SLSp = 0.f;
  __syncthreads();
  if (tid < 64){
    float p = 0.f;
    #pragma unroll
    for (int k = 0; k < 12; ++k) p += ls_g[k*64 + tid];
    atomicAdd(SLSp, p);
  }

  // H-part B-fragments: loaded ONCE, register-resident
  s8v hfr[4][4];
  #pragma unroll
  for (int nt = 0; nt < 4; ++nt){
    int b = rowbase + ng*64 + nt*16 + l15;
    #pragma unroll
    for (int kkh = 0; kkh < 4; ++kkh){
      const float* hp = Hg + (size_t)b*128 + kkh*32 + lq*8;
      f4v a = *(const f4v*)hp;
      f4v c = *(const f4v*)(hp + 4);
      s8v r;
      r[0]=f2bf(a[0]); r[1]=f2bf(a[1]); r[2]=f2bf(a[2]); r[3]=f2bf(a[3]);
      r[4]=f2bf(c[0]); r[5]=f2bf(c[1]); r[6]=f2bf(c[2]); r[7]=f2bf(c[3]);
      hfr[nt][kkh] = r;
    }
  }

  // prologue: stage MLP0 chunk0 weights + biases; barriers below cover visibility
  s8v w2cur[4];
  {
    MP p0 = getmp(0, wbf, s1W1f, s1W2f, s2W1f, s2W2f, s1b1, s1b2, s2b1, s2b2);
    u4v wt[5]; f4v wtf[10];
    issue_w1<USEBF>(p0, 0, tid, wt, wtf);
    write_w1<USEBF>(sm, 0, tid, wt, wtf);
    B1L[tid] = p0.b1[tid];
    if (tid < 64) B2L[tid] = p0.b2[tid];
    load_w2<USEBF>(p0, 0, hw, l15, lq, w2cur);
  }

  for (int m = 0; m < 24; ++m){
    if (!(m & 1)){
      int blk = m >> 1;
      if (tid < 64){
        PERM[tid] = perms[blk*64 + tid];
        ELS[tid]  = __expf(ls_g[blk*64 + tid]);
        BIV[tid]  = bi_g[blk*64 + tid];
      }
      __syncthreads();
      // permute + affine on XFT (read-all / barrier / write-all)
      {
        int d = lane, bg = wave;
        int pd = PERM[d];
        f4v v[4];
        #pragma unroll
        for (int i = 0; i < 4; ++i)
          v[i] = *(const f4v*)(XFT + pd*XFT_S + bg*16 + 4*i);
        __syncthreads();
        float e = ELS[d], bi = BIV[d];
        #pragma unroll
        for (int i = 0; i < 4; ++i){
          #pragma unroll
          for (int jj = 0; jj < 4; ++jj) v[i][jj] = fmaf(v[i][jj], e, bi);
          *(f4v*)(XFT + d*XFT_S + bg*16 + 4*i) = v[i];
        }
      }
      __syncthreads();
    }
    MP cur = getmp(m, wbf, s1W1f, s1W2f, s2W1f, s2W2f, s1b1, s1b2, s2b1, s2b2);
    MP nxt = getmp(m < 23 ? m + 1 : 23, wbf, s1W1f, s1W2f, s2W1f, s2W2f, s1b1, s1b2, s2b1, s2b2);
    mlp_body<USEBF>(sm, tid, m, cur, nxt, hfr, w2cur);
  }

  // output: transpose back, coalesced global writes
  {
    int b = tid >> 2, j = tid & 3;
    float* dst = outz + (size_t)(rowbase + b)*64 + j*16;
    #pragma unroll
    for (int i = 0; i < 4; ++i){
      f4v w;
      #pragma unroll
      for (int jj = 0; jj < 4; ++jj)
        w[jj] = XFT[(j*16 + 4*i + jj)*XFT_S + b];
      *(f4v*)(dst + 4*i) = w;
    }
  }
  if (tid < 128) outlj[rowbase + tid] = LOGJ[tid] + *SLSp;
}

extern "C" void kernel_launch(void* const* d_in, const int* in_sizes, int n_in,
                              void* d_out, int out_size, void* d_ws, size_t ws_size,
                              hipStream_t stream)
{
  const float* q    = (const float*)d_in[0];
  const float* Hg   = (const float*)d_in[1];
  const int*   perms= (const int*)  d_in[2];
  const float* ls   = (const float*)d_in[3];
  const float* bi   = (const float*)d_in[4];
  const float* s1W1 = (const float*)d_in[5];
  const float* s1b1 = (const float*)d_in[6];
  const float* s1W2 = (const float*)d_in[7];
  const float* s1b2 = (const float*)d_in[8];
  const float* s2W1 = (const float*)d_in[9];
  const float* s2b1 = (const float*)d_in[10];
  const float* s2W2 = (const float*)d_in[11];
  const float* s2b2 = (const float*)d_in[12];
  float* outz  = (float*)d_out;
  float* outlj = outz + (size_t)B_ROWS * 64;

  int usebf = (ws_size >= (size_t)W_TOTAL * 2) ? 1 : 0;
  unsigned short* wbf = (unsigned short*)d_ws;
  if (usebf){
    cvtw<<<2688, 1024, 0, stream>>>(s1W1, s1W2, s2W1, s2W2, wbf);
    cinn_t<1><<<256, 512, 0, stream>>>(q, Hg, perms, ls, bi,
                                       s1b1, s1b2, s2b1, s2b2,
                                       wbf, s1W1, s1W2, s2W1, s2W2,
                                       outz, outlj);
  } else {
    cinn_t<0><<<256, 512, 0, stream>>>(q, Hg, perms, ls, bi,
                                       s1b1, s1b2, s2b1, s2b2,
                                       wbf, s1W1, s1W2, s2W1, s2W2,
                                       outz, outlj);
  }
}

// Round 5
// 299.209 us; speedup vs baseline: 2.1911x; 1.0015x over previous
//
#include <hip/hip_runtime.h>
#include <hip/hip_bf16.h>
#include <math.h>

#define B_ROWS 32768

typedef __attribute__((ext_vector_type(8)))  short        s8v;
typedef __attribute__((ext_vector_type(4)))  float        f4v;
typedef __attribute__((ext_vector_type(2)))  unsigned int u2v;
typedef __attribute__((ext_vector_type(4)))  unsigned int u4v;

__device__ __forceinline__ short f2bf(float f){            // f32 -> bf16 RNE
  unsigned u = __builtin_bit_cast(unsigned, f);
  u = (u + 0x7fffu + ((u >> 16) & 1u)) >> 16;
  return (short)u;
}
__device__ __forceinline__ unsigned pk2(float a, float b){
  return (unsigned)(unsigned short)f2bf(a) | ((unsigned)(unsigned short)f2bf(b) << 16);
}
__device__ __forceinline__ float bf_lo(unsigned u){ return __builtin_bit_cast(float, u << 16); }
__device__ __forceinline__ float bf_hi(unsigned u){ return __builtin_bit_cast(float, u & 0xffff0000u); }

#define MFMA16(A,B,C) __builtin_amdgcn_mfma_f32_16x16x32_bf16((A),(B),(C),0,0,0)

// ---------------- LDS layout (bytes) ----------------
#define OXFT 0        // f32 [64][132] x-state transposed [dim][batch]
#define XFT_S 132
#define OHB  33792    // bf16 [128][136] hidden chunk (per-wave disjoint regions)
#define HB_S 136
#define OW1  68608    // 2 x bf16 [128][168] W1 chunk double buffer
#define W1BUF 43008
#define W1_S 168
#define OB1  154624   // 2 x f32[512] b1 double buffer
#define OB2  158720   // 2 x f32[64]  b2 double buffer
#define OLJ  159232   // f32[128]
#define OPERM 159744  // int[64]
#define OELS 160000   // f32[64]
#define OBIV 160256   // f32[64]
#define OSLS 160512   // f32 scalar
#define SM_SZ 160528

// reduce slots: bf16 [128][68] each (17408 B). Slots 0,1 alias dead W1 buf1;
// slots 2,3 alias dead HB. Liveness: written only after post-chunk3 barrier,
// consumed in coupling before next MLP touches buf1/HB.
#define SL_S 68
#define SLOT_B 17408

// ws (bf16 weights) element offsets
#define O_S1W1 0
#define O_S1W2 983040
#define O_S2W1 1376256
#define O_S2W2 2359296
#define W_TOTAL 2752512

__global__ void cvtw(const float* __restrict__ s1w1, const float* __restrict__ s1w2,
                     const float* __restrict__ s2w1, const float* __restrict__ s2w2,
                     unsigned short* __restrict__ dst)
{
  long t = (long)blockIdx.x * blockDim.x + threadIdx.x;
  if (t >= W_TOTAL) return;
  float v;
  if      (t < O_S1W2) v = s1w1[t];
  else if (t < O_S2W1) v = s1w2[t - O_S1W2];
  else if (t < O_S2W2) v = s2w1[t - O_S2W1];
  else                 v = s2w2[t - O_S2W2];
  dst[t] = (unsigned short)f2bf(v);
}

template<int USEBF>
__device__ __forceinline__ s8v ldw(const unsigned short* wb, const float* wf, int off){
  if (USEBF){
    return *(const s8v*)(wb + off);
  } else {
    f4v a = *(const f4v*)(wf + off);
    f4v b = *(const f4v*)(wf + off + 4);
    s8v r;
    r[0]=f2bf(a[0]); r[1]=f2bf(a[1]); r[2]=f2bf(a[2]); r[3]=f2bf(a[3]);
    r[4]=f2bf(b[0]); r[5]=f2bf(b[1]); r[6]=f2bf(b[2]); r[7]=f2bf(b[3]);
    return r;
  }
}

struct MP { const unsigned short* w1b; const float* w1f;
            const unsigned short* w2b; const float* w2f;
            const float* b1; const float* b2; };

__device__ __forceinline__ MP getmp(int m, const unsigned short* wbf,
    const float* s1W1f, const float* s1W2f, const float* s2W1f, const float* s2W2f,
    const float* s1b1, const float* s1b2, const float* s2b1, const float* s2b2)
{
  int blk = m >> 1;
  MP r;
  if (m & 1){
    r.w1b = wbf + O_S1W1 + (size_t)blk*81920; r.w1f = s1W1f + (size_t)blk*81920;
    r.w2b = wbf + O_S1W2 + (size_t)blk*32768; r.w2f = s1W2f + (size_t)blk*32768;
    r.b1 = s1b1 + blk*512; r.b2 = s1b2 + blk*64;
  } else {
    r.w1b = wbf + O_S2W1 + (size_t)blk*81920; r.w1f = s2W1f + (size_t)blk*81920;
    r.w2b = wbf + O_S2W2 + (size_t)blk*32768; r.w2f = s2W2f + (size_t)blk*32768;
    r.b1 = s2b1 + blk*512; r.b2 = s2b2 + blk*64;
  }
  return r;
}

// issue coalesced global loads of one 128-hidden W1 chunk into registers
template<int USEBF>
__device__ __forceinline__ void issue_w1(const MP& p, int cchunk, int tid,
                                         u4v wt[5], f4v wtf[10])
{
  if (USEBF){
    const unsigned short* s = p.w1b + cchunk*20480;
    #pragma unroll
    for (int k = 0; k < 5; ++k) wt[k] = *(const u4v*)(s + (size_t)(k*512+tid)*8);
  } else {
    const float* s = p.w1f + cchunk*20480;
    #pragma unroll
    for (int k = 0; k < 10; ++k) wtf[k] = *(const f4v*)(s + (size_t)(k*512+tid)*4);
  }
}

template<int USEBF>
__device__ __forceinline__ void write_w1(char* sm, int buf, int tid,
                                         const u4v wt[5], const f4v wtf[10])
{
  short* W1n = (short*)(sm + OW1 + buf*W1BUF);
  if (USEBF){
    #pragma unroll
    for (int k = 0; k < 5; ++k){
      int i = k*512 + tid, row = i/20, c16 = i - row*20;
      *(u4v*)(W1n + row*W1_S + c16*8) = wt[k];
    }
  } else {
    #pragma unroll
    for (int k = 0; k < 10; ++k){
      int i = k*512 + tid, row = i/40, c4 = i - row*40;
      f4v v = wtf[k];
      *(u2v*)(W1n + row*W1_S + c4*4) = (u2v){pk2(v[0],v[1]), pk2(v[2],v[3])};
    }
  }
}

// W2 A-frags: all 4 out-tiles, k-slice = this wave's 32 hidden rows of chunk c
template<int USEBF>
__device__ __forceinline__ void load_w2(const MP& p, int c, int hw, int l15, int lq, s8v w2o[4]){
  #pragma unroll
  for (int ot = 0; ot < 4; ++ot)
    w2o[ot] = ldw<USEBF>(p.w2b, p.w2f, (ot*16 + l15)*512 + c*128 + hw*32 + lq*8);
}

// ---- one MLP: h^T = relu(W1 x^T + b1); r^T = W2 h^T + b2; coupling ----
template<int USEBF>
__device__ __forceinline__ void mlp_body(char* sm, int tid, int m,
    const MP& cur, const MP& nxt, const s8v hfr[4][4], s8v w2cur[4])
{
  const int lane = tid & 63, wave = tid >> 6;
  const int hw = wave >> 1, ng = wave & 1;
  const int l15 = lane & 15, lq = lane >> 4;
  const int bp = m & 1;
  float* XFT = (float*)(sm + OXFT);
  short* HB  = (short*)(sm + OHB);
  float* B1L = (float*)(sm + OB1);
  float* B2L = (float*)(sm + OB2);
  float* LOGJ= (float*)(sm + OLJ);

  // x-part B-frags straight from XFT (dims xbase..xbase+31)
  const int xbase = bp ? 0 : 32;
  s8v xk[4];
  #pragma unroll
  for (int nt = 0; nt < 4; ++nt){
    int b = ng*64 + nt*16 + l15;
    s8v v;
    #pragma unroll
    for (int i = 0; i < 8; ++i)
      v[i] = f2bf(XFT[(xbase + lq*8 + i)*XFT_S + b]);
    xk[nt] = v;
  }

  // GEMM2 k-partial accumulators: all 4 out-tiles x 4 batch-tiles.
  // b2 carried only by hw==0 waves (others init 0).
  f4v racc[4][4];
  #pragma unroll
  for (int ot = 0; ot < 4; ++ot){
    f4v bv = (f4v){0.f,0.f,0.f,0.f};
    if (hw == 0) bv = *(const f4v*)(B2L + bp*64 + ot*16 + lq*4);
    #pragma unroll
    for (int nt = 0; nt < 4; ++nt) racc[ot][nt] = bv;
  }

  #pragma unroll
  for (int c = 0; c < 4; ++c){
    // prefetch next W1 chunk (global -> regs); commit to LDS at end of chunk
    u4v wt[5]; f4v wtf[10];
    const MP& pn = (c < 3) ? cur : nxt;
    const int cn = (c < 3) ? c + 1 : 0;
    issue_w1<USEBF>(pn, cn, tid, wt, wtf);
    float b1t = 0.f, b2t = 0.f;
    if (c == 3){
      b1t = nxt.b1[tid];
      if (tid < 64) b2t = nxt.b2[tid];
    }

    // ---- GEMM1 chunk c: hidden rows c*128 + hw*32 + {0,16}
    const short* W1c = (const short*)(sm + OW1 + (c&1)*W1BUF);
    f4v acc[2][4];
    #pragma unroll
    for (int mt = 0; mt < 2; ++mt){
      f4v bv = *(const f4v*)(B1L + bp*512 + c*128 + hw*32 + mt*16 + lq*4);
      #pragma unroll
      for (int nt = 0; nt < 4; ++nt) acc[mt][nt] = bv;
    }
    #pragma unroll
    for (int kk = 0; kk < 5; ++kk){
      s8v a0 = *(const s8v*)(W1c + (hw*32 +  0 + l15)*W1_S + kk*32 + lq*8);
      s8v a1 = *(const s8v*)(W1c + (hw*32 + 16 + l15)*W1_S + kk*32 + lq*8);
      #pragma unroll
      for (int nt = 0; nt < 4; ++nt){
        s8v bb = (kk == 0) ? xk[nt] : hfr[nt][kk-1];
        acc[0][nt] = MFMA16(a0, bb, acc[0][nt]);
        acc[1][nt] = MFMA16(a1, bb, acc[1][nt]);
      }
    }
    // relu + pack -> own HB region (rows ng*64.., cols hw*32..) — no cross-wave sharing
    #pragma unroll
    for (int mt = 0; mt < 2; ++mt)
      #pragma unroll
      for (int nt = 0; nt < 4; ++nt){
        float h0 = fmaxf(acc[mt][nt][0],0.f), h1 = fmaxf(acc[mt][nt][1],0.f);
        float h2 = fmaxf(acc[mt][nt][2],0.f), h3 = fmaxf(acc[mt][nt][3],0.f);
        *(u2v*)(HB + (ng*64 + nt*16 + l15)*HB_S + hw*32 + mt*16 + lq*4) = (u2v){pk2(h0,h1), pk2(h2,h3)};
      }
    // ---- GEMM2 k-slice: read back OWN rows as B-frags (in-wave, no barrier)
    #pragma unroll
    for (int nt = 0; nt < 4; ++nt){
      s8v bb = *(const s8v*)(HB + (ng*64 + nt*16 + l15)*HB_S + hw*32 + lq*8);
      #pragma unroll
      for (int ot = 0; ot < 4; ++ot)
        racc[ot][nt] = MFMA16(w2cur[ot], bb, racc[ot][nt]);
    }
    // commit staged W1 (other buffer), stage next biases, reload w2cur for next chunk
    write_w1<USEBF>(sm, cn & 1, tid, wt, wtf);
    if (c == 3){
      B1L[(bp^1)*512 + tid] = b1t;
      if (tid < 64) B2L[(bp^1)*64 + tid] = b2t;
    }
    load_w2<USEBF>(pn, cn, hw, l15, lq, w2cur);
    __syncthreads();
  }

  // ---- reduce k-partials: every wave writes its slot (bf16), slots alias dead buf1/HB
  {
    short* SL = (hw < 2) ? (short*)(sm + OW1 + W1BUF + hw*SLOT_B)
                         : (short*)(sm + OHB + (hw-2)*SLOT_B);
    #pragma unroll
    for (int ot = 0; ot < 4; ++ot)
      #pragma unroll
      for (int nt = 0; nt < 4; ++nt)
        *(u2v*)(SL + (ng*64 + nt*16 + l15)*SL_S + ot*16 + lq*4) =
          (u2v){pk2(racc[ot][nt][0], racc[ot][nt][1]), pk2(racc[ot][nt][2], racc[ot][nt][3])};
  }
  __syncthreads();

  // ---- coupling: sum 4 slots, le = 0.636*atan(rL); y = exp(le)*x_half + rR
  {
    int b = tid & 127, og = tid >> 7;
    float le[8] = {0,0,0,0,0,0,0,0}, ra[8] = {0,0,0,0,0,0,0,0};
    #pragma unroll
    for (int mslot = 0; mslot < 4; ++mslot){
      const short* SL = (mslot < 2) ? (const short*)(sm + OW1 + W1BUF + mslot*SLOT_B)
                                    : (const short*)(sm + OHB + (mslot-2)*SLOT_B);
      u2v L0 = *(const u2v*)(SL + b*SL_S + og*8);
      u2v L1 = *(const u2v*)(SL + b*SL_S + og*8 + 4);
      u2v R0 = *(const u2v*)(SL + b*SL_S + 32 + og*8);
      u2v R1 = *(const u2v*)(SL + b*SL_S + 32 + og*8 + 4);
      le[0]+=bf_lo(L0[0]); le[1]+=bf_hi(L0[0]); le[2]+=bf_lo(L0[1]); le[3]+=bf_hi(L0[1]);
      le[4]+=bf_lo(L1[0]); le[5]+=bf_hi(L1[0]); le[6]+=bf_lo(L1[1]); le[7]+=bf_hi(L1[1]);
      ra[0]+=bf_lo(R0[0]); ra[1]+=bf_hi(R0[0]); ra[2]+=bf_lo(R0[1]); ra[3]+=bf_hi(R0[1]);
      ra[4]+=bf_lo(R1[0]); ra[5]+=bf_hi(R1[0]); ra[6]+=bf_lo(R1[1]); ra[7]+=bf_hi(R1[1]);
    }
    float part = 0.f;
    #pragma unroll
    for (int j = 0; j < 8; ++j){
      float l = 0.636f * atanf(le[j]);
      int d = bp*32 + og*8 + j;
      float y = __expf(l) * XFT[d*XFT_S + b] + ra[j];
      XFT[d*XFT_S + b] = y;
      part += l;
    }
    atomicAdd(&LOGJ[b], part);
  }
  __syncthreads();
}

template<int USEBF>
__global__ __launch_bounds__(512, 2) void cinn_t(
    const float* __restrict__ q, const float* __restrict__ Hg,
    const int* __restrict__ perms,
    const float* __restrict__ ls_g, const float* __restrict__ bi_g,
    const float* __restrict__ s1b1, const float* __restrict__ s1b2,
    const float* __restrict__ s2b1, const float* __restrict__ s2b2,
    const unsigned short* __restrict__ wbf,
    const float* __restrict__ s1W1f, const float* __restrict__ s1W2f,
    const float* __restrict__ s2W1f, const float* __restrict__ s2W2f,
    float* __restrict__ outz, float* __restrict__ outlj)
{
  __shared__ __align__(16) char sm[SM_SZ];
  const int tid = threadIdx.x;
  const int rowbase = blockIdx.x * 128;
  const int lane = tid & 63, wave = tid >> 6;
  const int hw = wave >> 1, ng = wave & 1;
  const int l15 = lane & 15, lq = lane >> 4;

  float* XFT = (float*)(sm + OXFT);
  float* B1L = (float*)(sm + OB1);
  float* B2L = (float*)(sm + OB2);
  float* LOGJ = (float*)(sm + OLJ);
  int*   PERM = (int*)(sm + OPERM);
  float* ELS  = (float*)(sm + OELS);
  float* BIV  = (float*)(sm + OBIV);
  float* SLSp = (float*)(sm + OSLS);

  // init XFT from q (coalesced read, strided LDS write, once)
  {
    int b = tid >> 2, j = tid & 3;
    const float* src = q + (size_t)(rowbase + b)*64 + j*16;
    #pragma unroll
    for (int i = 0; i < 4; ++i){
      f4v v = *(const f4v*)(src + 4*i);
      #pragma unroll
      for (int jj = 0; jj < 4; ++jj)
        XFT[(j*16 + 4*i + jj)*XFT_S + b] = v[jj];
    }
  }
  if (tid < 128) LOGJ[tid] = 0.f;
  if (tid == 0)  *SLSp = 0.f;
  __syncthreads();
  if (tid < 64){
    float p = 0.f;
    #pragma unroll
    for (int k = 0; k < 12; ++k) p += ls_g[k*64 + tid];
    atomicAdd(SLSp, p);
  }

  // H-part B-fragments: loaded ONCE, register-resident
  s8v hfr[4][4];
  #pragma unroll
  for (int nt = 0; nt < 4; ++nt){
    int b = rowbase + ng*64 + nt*16 + l15;
    #pragma unroll
    for (int kkh = 0; kkh < 4; ++kkh){
      const float* hp = Hg + (size_t)b*128 + kkh*32 + lq*8;
      f4v a = *(const f4v*)hp;
      f4v c = *(const f4v*)(hp + 4);
      s8v r;
      r[0]=f2bf(a[0]); r[1]=f2bf(a[1]); r[2]=f2bf(a[2]); r[3]=f2bf(a[3]);
      r[4]=f2bf(c[0]); r[5]=f2bf(c[1]); r[6]=f2bf(c[2]); r[7]=f2bf(c[3]);
      hfr[nt][kkh] = r;
    }
  }

  // prologue: stage MLP0 chunk0 weights + biases
  s8v w2cur[4];
  {
    MP p0 = getmp(0, wbf, s1W1f, s1W2f, s2W1f, s2W2f, s1b1, s1b2, s2b1, s2b2);
    u4v wt[5]; f4v wtf[10];
    issue_w1<USEBF>(p0, 0, tid, wt, wtf);
    write_w1<USEBF>(sm, 0, tid, wt, wtf);
    B1L[tid] = p0.b1[tid];
    if (tid < 64) B2L[tid] = p0.b2[tid];
    load_w2<USEBF>(p0, 0, hw, l15, lq, w2cur);
  }

  for (int m = 0; m < 24; ++m){
    if (!(m & 1)){
      int blk = m >> 1;
      if (tid < 64){
        PERM[tid] = perms[blk*64 + tid];
        ELS[tid]  = __expf(ls_g[blk*64 + tid]);
        BIV[tid]  = bi_g[blk*64 + tid];
      }
      __syncthreads();
      // permute + affine on XFT (read-all / barrier / write-all)
      {
        int d = lane, bg = wave;
        int pd = PERM[d];
        f4v v[4];
        #pragma unroll
        for (int i = 0; i < 4; ++i)
          v[i] = *(const f4v*)(XFT + pd*XFT_S + bg*16 + 4*i);
        __syncthreads();
        float e = ELS[d], bi = BIV[d];
        #pragma unroll
        for (int i = 0; i < 4; ++i){
          #pragma unroll
          for (int jj = 0; jj < 4; ++jj) v[i][jj] = fmaf(v[i][jj], e, bi);
          *(f4v*)(XFT + d*XFT_S + bg*16 + 4*i) = v[i];
        }
      }
      __syncthreads();
    }
    MP cur = getmp(m, wbf, s1W1f, s1W2f, s2W1f, s2W2f, s1b1, s1b2, s2b1, s2b2);
    MP nxt = getmp(m < 23 ? m + 1 : 23, wbf, s1W1f, s1W2f, s2W1f, s2W2f, s1b1, s1b2, s2b1, s2b2);
    mlp_body<USEBF>(sm, tid, m, cur, nxt, hfr, w2cur);
  }

  // output: transpose back, coalesced global writes
  {
    int b = tid >> 2, j = tid & 3;
    float* dst = outz + (size_t)(rowbase + b)*64 + j*16;
    #pragma unroll
    for (int i = 0; i < 4; ++i){
      f4v w;
      #pragma unroll
      for (int jj = 0; jj < 4; ++jj)
        w[jj] = XFT[(j*16 + 4*i + jj)*XFT_S + b];
      *(f4v*)(dst + 4*i) = w;
    }
  }
  if (tid < 128) outlj[rowbase + tid] = LOGJ[tid] + *SLSp;
}

extern "C" void kernel_launch(void* const* d_in, const int* in_sizes, int n_in,
                              void* d_out, int out_size, void* d_ws, size_t ws_size,
                              hipStream_t stream)
{
  const float* q    = (const float*)d_in[0];
  const float* Hg   = (const float*)d_in[1];
  const int*   perms= (const int*)  d_in[2];
  const float* ls   = (const float*)d_in[3];
  const float* bi   = (const float*)d_in[4];
  const float* s1W1 = (const float*)d_in[5];
  const float* s1b1 = (const float*)d_in[6];
  const float* s1W2 = (const float*)d_in[7];
  const float* s1b2 = (const float*)d_in[8];
  const float* s2W1 = (const float*)d_in[9];
  const float* s2b1 = (const float*)d_in[10];
  const float* s2W2 = (const float*)d_in[11];
  const float* s2b2 = (const float*)d_in[12];
  float* outz  = (float*)d_out;
  float* outlj = outz + (size_t)B_ROWS * 64;

  int usebf = (ws_size >= (size_t)W_TOTAL * 2) ? 1 : 0;
  unsigned short* wbf = (unsigned short*)d_ws;
  if (usebf){
    cvtw<<<2688, 1024, 0, stream>>>(s1W1, s1W2, s2W1, s2W2, wbf);
    cinn_t<1><<<256, 512, 0, stream>>>(q, Hg, perms, ls, bi,
                                       s1b1, s1b2, s2b1, s2b2,
                                       wbf, s1W1, s1W2, s2W1, s2W2,
                                       outz, outlj);
  } else {
    cinn_t<0><<<256, 512, 0, stream>>>(q, Hg, perms, ls, bi,
                                       s1b1, s1b2, s2b1, s2b2,
                                       wbf, s1W1, s1W2, s2W1, s2W2,
                                       outz, outlj);
  }
}